// Round 5
// baseline (2322.342 us; speedup 1.0000x reference)
//
#include <hip/hip_runtime.h>
#include <math.h>

#define N_PTS 131072
#define HID   256

typedef __attribute__((ext_vector_type(8))) _Float16 f16x8;
typedef __attribute__((ext_vector_type(4))) float    f32x4;
typedef unsigned int u32;
typedef __attribute__((address_space(1))) const u32 gu32;
typedef __attribute__((address_space(3))) u32       lu32;

// LDS map (dynamic, 160 KiB): act_hi[128][256] f16 (64KB) | W ring (3 x 32KB)
#define LDS_HI  0
#define LDS_W   65536
#define LDS_SZ  163840
#define LO_SCALE 4096.0f
#define LO_INV   (1.0f/4096.0f)

// act plane: [row][k] f16, XOR swizzle -> b128 A-frag reads conflict-optimal
__device__ __forceinline__ int act_off(int row, int kbyte) {
    return row * 512 + (kbyte ^ ((row & 7) << 4));
}
// W slab in LDS: [n][32k] f16 (transposed), slot XOR on (n>>1)
__device__ __forceinline__ int w_off(int n, int kg) {
    return n * 64 + ((kg ^ ((n >> 1) & 3)) << 4);
}
__device__ __forceinline__ float fast_tanh(float z) {
    float zc = fminf(fmaxf(z, -15.0f), 15.0f);
    float t  = __expf(2.0f * zc);
    return __fdividef(t - 1.0f, t + 1.0f);
}
__device__ __forceinline__ void split_hl(float v, _Float16 &hi, _Float16 &lo) {
    hi = (_Float16)v;
    lo = (_Float16)((v - (float)hi) * LO_SCALE);
}

// Pre-split W1..W3 into f16 hi/lo, transposed to [n][k], LDS swizzle pre-applied.
// d_ws: [layer 0..2][slab 0..7] x 32KB = [hi 16KB][lo 16KB]. 768KB total.
__global__ void prep_w(const float* __restrict__ W1, const float* __restrict__ W2,
                       const float* __restrict__ W3, char* __restrict__ ws)
{
    int idx = blockIdx.x * 256 + threadIdx.x;
    int l = idx >> 16;
    int e = idx & 65535;
    int k = e >> 8, n = e & 255;
    const float* W = (l == 0) ? W1 : (l == 1) ? W2 : W3;
    float w = W[e];
    _Float16 hi, lo;
    split_hl(w, hi, lo);
    int kk = k & 31;
    int byte_in = w_off(n, kk >> 3) + (kk & 7) * 2;
    char* base = ws + (size_t)(l * 8 + (k >> 5)) * 32768;
    *(_Float16*)(base + byte_in)         = hi;
    *(_Float16*)(base + 16384 + byte_in) = lo;
}

// Persistent fused PINN. A = f16-hi; W = f16 hi/lo. 128 GEMM rows per tile,
// 8 waves (wave w owns cols [32w,32w+32)), 3-deep W ring with counted vmcnt:
// slab body = { vmcnt(4) ; s_barrier ; issue stage(G+2) ; ds_read frags ; MFMA }.
template<int S, int PTS, int NT>
__global__ void __launch_bounds__(512, 1)
pinn_persist(const float* __restrict__ W0, const float* __restrict__ b0,
             const float* __restrict__ b1, const float* __restrict__ b2,
             const float* __restrict__ b3,
             const float* __restrict__ W4, const float* __restrict__ b4,
             const char* __restrict__ wpre,
             const float* __restrict__ tx, float* __restrict__ out)
{
    extern __shared__ char lds[];
    const int tid  = threadIdx.x;
    const int lane = tid & 63;
    const int wid  = tid >> 6;
    constexpr int NTOT = NT * 24;      // total slab stream length
    constexpr int CG = 512 / PTS;
    constexpr int NC = 256 / CG;
    const int ep  = tid / CG;
    const int ec0 = (tid % CG) * NC;
    const int wcb = wid * 32;

    // bias preload (2 cols per lane per layer)
    const int cA = wcb + (lane & 15);
    float bc[3][2];
    bc[0][0] = b1[cA]; bc[0][1] = b1[cA + 16];
    bc[1][0] = b2[cA]; bc[1][1] = b2[cA + 16];
    bc[2][0] = b3[cA]; bc[2][1] = b3[cA + 16];

    // prologue: issue stages for slabs 0 and 1 (ring slots 0,1)
    #pragma unroll
    for (int f = 0; f < 2; ++f) {
        const char* src = wpre + (size_t)f * 32768;
        char* dst = lds + LDS_W + f * 32768;
        #pragma unroll
        for (int q = 0; q < 4; ++q) {
            int o = (wid * 4 + q) * 1024;
            __builtin_amdgcn_global_load_lds((gu32*)(src + o + lane * 16),
                                             (lu32*)(dst + o), 16, 0, 0);
        }
    }

    for (int t = 0; t < NT; ++t) {
        const int pbase = (t * 256 + blockIdx.x) * PTS;

        // ---------------- layer 0: 2 -> 256 (elementwise into LDS act-hi) ----------------
        {
            const float tt = tx[2 * (pbase + ep) + 0];
            const float xx = tx[2 * (pbase + ep) + 1];
            for (int cb = ec0; cb < ec0 + NC; cb += 8) {
                alignas(16) float w0r[8], w1r[8], bb[8];
                *(f32x4*)&w0r[0] = *(const f32x4*)(W0 + cb);
                *(f32x4*)&w0r[4] = *(const f32x4*)(W0 + cb + 4);
                *(f32x4*)&w1r[0] = *(const f32x4*)(W0 + HID + cb);
                *(f32x4*)&w1r[4] = *(const f32x4*)(W0 + HID + cb + 4);
                *(f32x4*)&bb[0]  = *(const f32x4*)(b0 + cb);
                *(f32x4*)&bb[4]  = *(const f32x4*)(b0 + cb + 4);
                f16x8 vhi[S];
                #pragma unroll
                for (int j = 0; j < 8; ++j) {
                    float z = fmaf(tt, w0r[j], fmaf(xx, w1r[j], bb[j]));
                    float h = fast_tanh(z);
                    float f1 = 1.0f - h * h;
                    vhi[0][j] = (_Float16)h;
                    if (S == 2) {
                        vhi[1][j] = (_Float16)(f1 * w0r[j]);
                    } else if (S == 4) {
                        float d1 = w0r[j] + w1r[j];
                        float d2 = w0r[j] - w1r[j];
                        float f2 = -2.0f * h * f1;
                        vhi[1][j] = (_Float16)(f1 * d1);
                        vhi[2][j] = (_Float16)(f1 * d2);
                        vhi[3][j] = (_Float16)(f2 * d1 * d2);
                    }
                }
                #pragma unroll
                for (int s2 = 0; s2 < S; ++s2) {
                    int row = s2 * PTS + ep;
                    *(f16x8*)(lds + LDS_HI + act_off(row, cb * 2)) = vhi[s2];
                }
            }
        }
        asm volatile("s_waitcnt lgkmcnt(0)" ::: "memory");
        __builtin_amdgcn_sched_barrier(0);
        __builtin_amdgcn_s_barrier();

        // ---------------- layers 1..3: 256 -> 256 (A-hi x W-hi/lo MFMA) ----------------
        #pragma unroll
        for (int l = 0; l < 3; ++l) {
            f32x4 am[8][2], al[8][2];
            #pragma unroll
            for (int rt = 0; rt < 8; ++rt)
                #pragma unroll
                for (int ct = 0; ct < 2; ++ct) {
                    am[rt][ct] = (f32x4){0.f, 0.f, 0.f, 0.f};
                    al[rt][ct] = (f32x4){0.f, 0.f, 0.f, 0.f};
                }

            for (int s = 0; s < 8; ++s) {
                const int flat = (t * 3 + l) * 8 + s;
                // counted wait: own slab's 4 loads complete; next slab's stay in flight
                if (flat == NTOT - 1) {
                    asm volatile("s_waitcnt vmcnt(0)" ::: "memory");
                } else {
                    asm volatile("s_waitcnt vmcnt(4)" ::: "memory");
                }
                __builtin_amdgcn_s_barrier();

                const int f2 = flat + 2;
                if (f2 < NTOT) {   // issue stage 2 slabs ahead into ring slot f2%3
                    const char* src = wpre + (size_t)(f2 % 24) * 32768;
                    char* dst = lds + LDS_W + (f2 % 3) * 32768;
                    #pragma unroll
                    for (int q = 0; q < 4; ++q) {
                        int o = (wid * 4 + q) * 1024;
                        __builtin_amdgcn_global_load_lds((gu32*)(src + o + lane * 16),
                                                         (lu32*)(dst + o), 16, 0, 0);
                    }
                }

                const int kbyte = s * 64 + ((lane >> 4) << 4);
                const char* wb = lds + LDS_W + (flat % 3) * 32768;
                f16x8 bhi[2], blo[2];
                #pragma unroll
                for (int ct = 0; ct < 2; ++ct) {
                    const int n  = wcb + ct * 16 + (lane & 15);
                    const int wo = w_off(n, lane >> 4);
                    bhi[ct] = *(const f16x8*)(wb + wo);
                    blo[ct] = *(const f16x8*)(wb + 16384 + wo);
                }
                __builtin_amdgcn_s_setprio(1);
                #pragma unroll
                for (int rt = 0; rt < 8; ++rt) {
                    const int row = rt * 16 + (lane & 15);
                    f16x8 ahi = *(const f16x8*)(lds + LDS_HI + act_off(row, kbyte));
                    am[rt][0] = __builtin_amdgcn_mfma_f32_16x16x32_f16(ahi, bhi[0], am[rt][0], 0, 0, 0);
                    am[rt][1] = __builtin_amdgcn_mfma_f32_16x16x32_f16(ahi, bhi[1], am[rt][1], 0, 0, 0);
                    al[rt][0] = __builtin_amdgcn_mfma_f32_16x16x32_f16(ahi, blo[0], al[rt][0], 0, 0, 0);
                    al[rt][1] = __builtin_amdgcn_mfma_f32_16x16x32_f16(ahi, blo[1], al[rt][1], 0, 0, 0);
                }
                __builtin_amdgcn_s_setprio(0);
            }
            __builtin_amdgcn_s_barrier();   // all waves done reading act for this layer

            // ---- in-register epilogue ----
            // C/D: row = rt*16 + (lane>>4)*4 + r, col = wcb + ct*16 + (lane&15)
            #pragma unroll
            for (int ct = 0; ct < 2; ++ct) {
                const int col = wcb + ct * 16 + (lane & 15);
                const float bias = bc[l][ct];
                #pragma unroll
                for (int r = 0; r < 4; ++r) {
                    const int pr = (lane >> 4) * 4 + r;
                    if (S == 4) {
                        #pragma unroll
                        for (int pp = 0; pp < 2; ++pp) {
                            float z0 = am[0 + pp][ct][r] + al[0 + pp][ct][r] * LO_INV + bias;
                            float z1 = am[2 + pp][ct][r] + al[2 + pp][ct][r] * LO_INV;
                            float z2 = am[4 + pp][ct][r] + al[4 + pp][ct][r] * LO_INV;
                            float zm = am[6 + pp][ct][r] + al[6 + pp][ct][r] * LO_INV;
                            float h  = fast_tanh(z0);
                            float f1 = 1.0f - h * h;
                            float f2 = -2.0f * h * f1;
                            int prow = pp * 16 + pr;
                            *(_Float16*)(lds + LDS_HI + act_off(prow,      col * 2)) = (_Float16)h;
                            *(_Float16*)(lds + LDS_HI + act_off(32 + prow, col * 2)) = (_Float16)(f1 * z1);
                            *(_Float16*)(lds + LDS_HI + act_off(64 + prow, col * 2)) = (_Float16)(f1 * z2);
                            *(_Float16*)(lds + LDS_HI + act_off(96 + prow, col * 2)) =
                                (_Float16)(fmaf(f1, zm, f2 * z1 * z2));
                        }
                    } else if (S == 2) {
                        #pragma unroll
                        for (int rtv = 0; rtv < 4; ++rtv) {
                            float z0 = am[rtv][ct][r]     + al[rtv][ct][r]     * LO_INV + bias;
                            float zd = am[rtv + 4][ct][r] + al[rtv + 4][ct][r] * LO_INV;
                            float h  = fast_tanh(z0);
                            float f1 = 1.0f - h * h;
                            int prow = rtv * 16 + pr;
                            *(_Float16*)(lds + LDS_HI + act_off(prow,      col * 2)) = (_Float16)h;
                            *(_Float16*)(lds + LDS_HI + act_off(64 + prow, col * 2)) = (_Float16)(f1 * zd);
                        }
                    } else {
                        #pragma unroll
                        for (int rt = 0; rt < 8; ++rt) {
                            float z0 = am[rt][ct][r] + al[rt][ct][r] * LO_INV + bias;
                            float h  = fast_tanh(z0);
                            *(_Float16*)(lds + LDS_HI + act_off(rt * 16 + pr, col * 2)) = (_Float16)h;
                        }
                    }
                }
            }
            asm volatile("s_waitcnt lgkmcnt(0)" ::: "memory");
            __builtin_amdgcn_sched_barrier(0);
            __builtin_amdgcn_s_barrier();
        }

        // ---------------- layer 4: 256 -> 1 ----------------
        if (S == 4) {
            const int p   = tid >> 4;     // 0..31, mixed stream rows 96..127
            const int seg = tid & 15;
            const int k0  = seg * 16;
            const int row = 96 + p;
            float d = 0.0f;
            #pragma unroll
            for (int kb = 0; kb < 16; kb += 8) {
                f16x8 h8 = *(const f16x8*)(lds + LDS_HI + act_off(row, (k0 + kb) * 2));
                alignas(16) float wv[8];
                *(f32x4*)&wv[0] = *(const f32x4*)(W4 + k0 + kb);
                *(f32x4*)&wv[4] = *(const f32x4*)(W4 + k0 + kb + 4);
                #pragma unroll
                for (int j = 0; j < 8; ++j) d = fmaf((float)h8[j], wv[j], d);
            }
            #pragma unroll
            for (int off = 8; off > 0; off >>= 1) d += __shfl_down(d, off, 16);
            if (seg == 0) out[0 * N_PTS + pbase + p] = d;              // u_tt - u_xx
        } else {
            const int row = tid >> 2;     // 0..127
            const int seg = tid & 3;
            const int k0  = seg * 64;
            float d = 0.0f;
            #pragma unroll
            for (int kb = 0; kb < 64; kb += 8) {
                f16x8 h8 = *(const f16x8*)(lds + LDS_HI + act_off(row, (k0 + kb) * 2));
                alignas(16) float wv[8];
                *(f32x4*)&wv[0] = *(const f32x4*)(W4 + k0 + kb);
                *(f32x4*)&wv[4] = *(const f32x4*)(W4 + k0 + kb + 4);
                #pragma unroll
                for (int j = 0; j < 8; ++j) d = fmaf((float)h8[j], wv[j], d);
            }
            d += __shfl_down(d, 2, 4);
            d += __shfl_down(d, 1, 4);
            if (seg == 0) {
                if (S == 2) {
                    if (row < 64) out[1 * N_PTS + pbase + row] = d + b4[0];        // u_phi
                    else          out[2 * N_PTS + pbase + (row - 64)] = d;         // du/dt
                } else {
                    out[3 * N_PTS + pbase + row] = d + b4[0];                      // u_bound
                }
            }
        }
        __builtin_amdgcn_s_barrier();   // act reads done before next tile's layer 0
    }
}

extern "C" void kernel_launch(void* const* d_in, const int* in_sizes, int n_in,
                              void* d_out, int out_size, void* d_ws, size_t ws_size,
                              hipStream_t stream) {
    const float* W0 = (const float*)d_in[0];
    const float* b0 = (const float*)d_in[1];
    const float* W1 = (const float*)d_in[2];
    const float* b1 = (const float*)d_in[3];
    const float* W2 = (const float*)d_in[4];
    const float* b2 = (const float*)d_in[5];
    const float* W3 = (const float*)d_in[6];
    const float* b3 = (const float*)d_in[7];
    const float* W4 = (const float*)d_in[8];
    const float* b4 = (const float*)d_in[9];
    const float* tx_eq    = (const float*)d_in[10];
    const float* tx_init  = (const float*)d_in[11];
    const float* tx_bound = (const float*)d_in[12];
    float* out = (float*)d_out;
    char* wpre = (char*)d_ws;     // needs 768KB

    hipFuncSetAttribute((const void*)pinn_persist<4,32,16>, hipFuncAttributeMaxDynamicSharedMemorySize, LDS_SZ);
    hipFuncSetAttribute((const void*)pinn_persist<2,64,8>,  hipFuncAttributeMaxDynamicSharedMemorySize, LDS_SZ);
    hipFuncSetAttribute((const void*)pinn_persist<1,128,4>, hipFuncAttributeMaxDynamicSharedMemorySize, LDS_SZ);

    prep_w<<<768, 256, 0, stream>>>(W1, W2, W3, wpre);
    pinn_persist<4,32,16><<<256, 512, LDS_SZ, stream>>>(W0,b0,b1,b2,b3,W4,b4,wpre,tx_eq,   out);
    pinn_persist<2,64,8> <<<256, 512, LDS_SZ, stream>>>(W0,b0,b1,b2,b3,W4,b4,wpre,tx_init, out);
    pinn_persist<1,128,4><<<256, 512, LDS_SZ, stream>>>(W0,b0,b1,b2,b3,W4,b4,wpre,tx_bound,out);
}

// Round 6
// 673.316 us; speedup vs baseline: 3.4491x; 3.4491x over previous
//
#include <hip/hip_runtime.h>
#include <math.h>

#define N_PTS 131072
#define HID   256

typedef __attribute__((ext_vector_type(8))) _Float16 f16x8;
typedef __attribute__((ext_vector_type(4))) float    f32x4;
typedef unsigned int u32;
typedef __attribute__((address_space(1))) const u32 gu32;
typedef __attribute__((address_space(3))) u32       lu32;

// LDS map (dynamic, 128 KiB): act_hi[128][256] f16 (64KB) | W double-buffer (2 x 32KB)
#define LDS_HI  0
#define LDS_W   65536
#define LDS_SZ  131072

// act plane: [row][k] f16, XOR swizzle -> b128 A-frag reads conflict-free
__device__ __forceinline__ int act_off(int row, int kbyte) {
    return row * 512 + (kbyte ^ ((row & 7) << 4));
}
// W period in LDS: [n][64k] f16 (transposed), 16B-slot XOR on (n&7) -> 2-way max
__device__ __forceinline__ int w_off64(int n, int kg) {
    return n * 128 + ((kg ^ (n & 7)) << 4);
}
__device__ __forceinline__ float fast_tanh(float z) {
    float zc = fminf(fmaxf(z, -15.0f), 15.0f);
    float t  = __expf(2.0f * zc);
    return __fdividef(t - 1.0f, t + 1.0f);
}

// Pre-cast W1..W3 to f16 (RN), transposed to [n][k], LDS swizzle pre-applied.
// d_ws: [layer 0..2][period 0..3] x 32KB. 384KB total.
__global__ void prep_w(const float* __restrict__ W1, const float* __restrict__ W2,
                       const float* __restrict__ W3, char* __restrict__ ws)
{
    int idx = blockIdx.x * 256 + threadIdx.x;     // 3*65536 elements
    int l = idx >> 16;
    int e = idx & 65535;
    int k = e >> 8, n = e & 255;
    const float* W = (l == 0) ? W1 : (l == 1) ? W2 : W3;
    float w = W[e];
    int period = k >> 6;
    int kk = k & 63;
    int byte_in = w_off64(n, kk >> 3) + (kk & 7) * 2;
    char* base = ws + (size_t)(l * 4 + period) * 32768;
    *(_Float16*)(base + byte_in) = (_Float16)w;
}

// Fused PINN forward + Taylor streams. A = f16 (RN); W = f16 (RN). fp32 accum.
// 128 GEMM rows/block; 8 waves; wave w owns cols [32w, 32w+32). BK=64 periods,
// double-buffered W, prefetch covered by the period's 32 MFMAs.
template<int S, int PTS>
__global__ void __launch_bounds__(512, 1)
pinn_mfma(const float* __restrict__ W0, const float* __restrict__ b0,
          const float* __restrict__ b1, const float* __restrict__ b2,
          const float* __restrict__ b3,
          const float* __restrict__ W4, const float* __restrict__ b4,
          const char* __restrict__ wpre,
          const float* __restrict__ tx, float* __restrict__ out)
{
    extern __shared__ char lds[];
    const int tid  = threadIdx.x;
    const int lane = tid & 63;
    const int wid  = tid >> 6;
    const int pbase = blockIdx.x * PTS;
    constexpr int CG = 512 / PTS;     // threads per point (layer 0)
    constexpr int NC = 256 / CG;      // cols per thread (layer 0)
    const int ep  = tid / CG;
    const int ec0 = (tid % CG) * NC;
    const int wcb = wid * 32;

    // ---------------- layer 0: 2 -> 256 (elementwise into LDS act-hi) ----------------
    {
        const float tt = tx[2 * (pbase + ep) + 0];
        const float xx = tx[2 * (pbase + ep) + 1];
        for (int cb = ec0; cb < ec0 + NC; cb += 8) {
            alignas(16) float w0r[8], w1r[8], bb[8];
            *(f32x4*)&w0r[0] = *(const f32x4*)(W0 + cb);
            *(f32x4*)&w0r[4] = *(const f32x4*)(W0 + cb + 4);
            *(f32x4*)&w1r[0] = *(const f32x4*)(W0 + HID + cb);
            *(f32x4*)&w1r[4] = *(const f32x4*)(W0 + HID + cb + 4);
            *(f32x4*)&bb[0]  = *(const f32x4*)(b0 + cb);
            *(f32x4*)&bb[4]  = *(const f32x4*)(b0 + cb + 4);
            f16x8 vhi[S];
            #pragma unroll
            for (int j = 0; j < 8; ++j) {
                float z = fmaf(tt, w0r[j], fmaf(xx, w1r[j], bb[j]));
                float h = fast_tanh(z);
                float f1 = 1.0f - h * h;
                vhi[0][j] = (_Float16)h;
                if (S == 2) {
                    vhi[1][j] = (_Float16)(f1 * w0r[j]);
                } else if (S == 4) {
                    float d1 = w0r[j] + w1r[j];
                    float d2 = w0r[j] - w1r[j];
                    float f2 = -2.0f * h * f1;
                    vhi[1][j] = (_Float16)(f1 * d1);
                    vhi[2][j] = (_Float16)(f1 * d2);
                    vhi[3][j] = (_Float16)(f2 * d1 * d2);
                }
            }
            #pragma unroll
            for (int s2 = 0; s2 < S; ++s2) {
                int row = s2 * PTS + ep;
                *(f16x8*)(lds + LDS_HI + act_off(row, cb * 2)) = vhi[s2];
            }
        }
    }

    // bias preload (2 cols per lane per layer)
    const int cA = wcb + (lane & 15);
    float bc[3][2];
    bc[0][0] = b1[cA]; bc[0][1] = b1[cA + 16];
    bc[1][0] = b2[cA]; bc[1][1] = b2[cA + 16];
    bc[2][0] = b3[cA]; bc[2][1] = b3[cA + 16];

    // stage period 0 into buf0 (32KB: 512 threads x 4 x 16B)
    {
        const char* src = wpre;
        char* dst = lds + LDS_W;
        #pragma unroll
        for (int q = 0; q < 4; ++q) {
            int o = (wid * 4 + q) * 1024;
            __builtin_amdgcn_global_load_lds((gu32*)(src + o + lane * 16),
                                             (lu32*)(dst + o), 16, 0, 0);
        }
    }
    __syncthreads();

    // ---------------- layers 1..3: 256 -> 256 (f16 MFMA, fp32 accum) ----------------
    #pragma unroll
    for (int l = 0; l < 3; ++l) {
        f32x4 am[8][2];
        #pragma unroll
        for (int rt = 0; rt < 8; ++rt)
            #pragma unroll
            for (int ct = 0; ct < 2; ++ct)
                am[rt][ct] = (f32x4){0.f, 0.f, 0.f, 0.f};

        for (int ph = 0; ph < 4; ++ph) {
            const int g = l * 4 + ph;
            if (g < 11) {   // prefetch next period into other buffer
                const char* src = wpre + (size_t)(g + 1) * 32768;
                char* dst = lds + LDS_W + ((g + 1) & 1) * 32768;
                #pragma unroll
                for (int q = 0; q < 4; ++q) {
                    int o = (wid * 4 + q) * 1024;
                    __builtin_amdgcn_global_load_lds((gu32*)(src + o + lane * 16),
                                                     (lu32*)(dst + o), 16, 0, 0);
                }
            }
            const char* wb = lds + LDS_W + (g & 1) * 32768;
            #pragma unroll
            for (int ks = 0; ks < 2; ++ks) {
                // B-frags: n = wcb + ct*16 + (lane&15), kg = ks*4 + (lane>>4)
                f16x8 bhi[2];
                #pragma unroll
                for (int ct = 0; ct < 2; ++ct) {
                    const int n = wcb + ct * 16 + (lane & 15);
                    bhi[ct] = *(const f16x8*)(wb + w_off64(n, ks * 4 + (lane >> 4)));
                }
                // A-frags: k = ph*64 + ks*32 + (lane>>4)*8 + j
                const int kbyte = ph * 128 + ks * 64 + ((lane >> 4) << 4);
                __builtin_amdgcn_s_setprio(1);
                #pragma unroll
                for (int rt = 0; rt < 8; ++rt) {
                    const int row = rt * 16 + (lane & 15);
                    f16x8 ahi = *(const f16x8*)(lds + LDS_HI + act_off(row, kbyte));
                    am[rt][0] = __builtin_amdgcn_mfma_f32_16x16x32_f16(ahi, bhi[0], am[rt][0], 0, 0, 0);
                    am[rt][1] = __builtin_amdgcn_mfma_f32_16x16x32_f16(ahi, bhi[1], am[rt][1], 0, 0, 0);
                }
                __builtin_amdgcn_s_setprio(0);
            }
            __syncthreads();   // prefetch drain covered by this period's MFMAs
        }

        // ---- in-register epilogue ----
        // C/D: row = rt*16 + (lane>>4)*4 + r, col = wcb + ct*16 + (lane&15)
        #pragma unroll
        for (int ct = 0; ct < 2; ++ct) {
            const int col = wcb + ct * 16 + (lane & 15);
            const float bias = bc[l][ct];
            #pragma unroll
            for (int r = 0; r < 4; ++r) {
                const int pr = (lane >> 4) * 4 + r;
                if (S == 4) {
                    // stream s2, point-half pp: tile rt = s2*2 + pp
                    #pragma unroll
                    for (int pp = 0; pp < 2; ++pp) {
                        float z0 = am[0 + pp][ct][r] + bias;
                        float z1 = am[2 + pp][ct][r];
                        float z2 = am[4 + pp][ct][r];
                        float zm = am[6 + pp][ct][r];
                        float h  = fast_tanh(z0);
                        float f1 = 1.0f - h * h;
                        float f2 = -2.0f * h * f1;
                        int prow = pp * 16 + pr;
                        *(_Float16*)(lds + LDS_HI + act_off(prow,      col * 2)) = (_Float16)h;
                        *(_Float16*)(lds + LDS_HI + act_off(32 + prow, col * 2)) = (_Float16)(f1 * z1);
                        *(_Float16*)(lds + LDS_HI + act_off(64 + prow, col * 2)) = (_Float16)(f1 * z2);
                        *(_Float16*)(lds + LDS_HI + act_off(96 + prow, col * 2)) =
                            (_Float16)(fmaf(f1, zm, f2 * z1 * z2));
                    }
                } else if (S == 2) {
                    // value tiles rt=0..3 (rows 0-63), deriv tiles rt+4 (rows 64-127)
                    #pragma unroll
                    for (int rtv = 0; rtv < 4; ++rtv) {
                        float z0 = am[rtv][ct][r] + bias;
                        float zd = am[rtv + 4][ct][r];
                        float h  = fast_tanh(z0);
                        float f1 = 1.0f - h * h;
                        int prow = rtv * 16 + pr;
                        *(_Float16*)(lds + LDS_HI + act_off(prow,      col * 2)) = (_Float16)h;
                        *(_Float16*)(lds + LDS_HI + act_off(64 + prow, col * 2)) = (_Float16)(f1 * zd);
                    }
                } else {
                    #pragma unroll
                    for (int rt = 0; rt < 8; ++rt) {
                        float z0 = am[rt][ct][r] + bias;
                        float h  = fast_tanh(z0);
                        *(_Float16*)(lds + LDS_HI + act_off(rt * 16 + pr, col * 2)) = (_Float16)h;
                    }
                }
            }
        }
        asm volatile("s_waitcnt lgkmcnt(0)" ::: "memory");
        __builtin_amdgcn_sched_barrier(0);
        __builtin_amdgcn_s_barrier();
    }

    // ---------------- layer 4: 256 -> 1 ----------------
    if (S == 4) {
        // only the mixed stream (rows 96..127) is needed
        const int p   = tid >> 4;     // 0..31
        const int seg = tid & 15;     // 16 lanes per row
        const int k0  = seg * 16;
        const int row = 96 + p;
        float d = 0.0f;
        #pragma unroll
        for (int kb = 0; kb < 16; kb += 8) {
            f16x8 h8 = *(const f16x8*)(lds + LDS_HI + act_off(row, (k0 + kb) * 2));
            alignas(16) float wv[8];
            *(f32x4*)&wv[0] = *(const f32x4*)(W4 + k0 + kb);
            *(f32x4*)&wv[4] = *(const f32x4*)(W4 + k0 + kb + 4);
            #pragma unroll
            for (int j = 0; j < 8; ++j) d = fmaf((float)h8[j], wv[j], d);
        }
        #pragma unroll
        for (int off = 8; off > 0; off >>= 1) d += __shfl_down(d, off, 16);
        if (seg == 0) out[0 * N_PTS + pbase + p] = d;              // u_tt - u_xx
    } else {
        const int row = tid >> 2;     // 0..127
        const int seg = tid & 3;      // 4 lanes per row
        const int k0  = seg * 64;
        float d = 0.0f;
        #pragma unroll
        for (int kb = 0; kb < 64; kb += 8) {
            f16x8 h8 = *(const f16x8*)(lds + LDS_HI + act_off(row, (k0 + kb) * 2));
            alignas(16) float wv[8];
            *(f32x4*)&wv[0] = *(const f32x4*)(W4 + k0 + kb);
            *(f32x4*)&wv[4] = *(const f32x4*)(W4 + k0 + kb + 4);
            #pragma unroll
            for (int j = 0; j < 8; ++j) d = fmaf((float)h8[j], wv[j], d);
        }
        d += __shfl_down(d, 2, 4);
        d += __shfl_down(d, 1, 4);
        if (seg == 0) {
            if (S == 2) {
                if (row < 64) out[1 * N_PTS + pbase + row] = d + b4[0];        // u_phi
                else          out[2 * N_PTS + pbase + (row - 64)] = d;         // du/dt
            } else {
                out[3 * N_PTS + pbase + row] = d + b4[0];                      // u_bound
            }
        }
    }
}

extern "C" void kernel_launch(void* const* d_in, const int* in_sizes, int n_in,
                              void* d_out, int out_size, void* d_ws, size_t ws_size,
                              hipStream_t stream) {
    const float* W0 = (const float*)d_in[0];
    const float* b0 = (const float*)d_in[1];
    const float* W1 = (const float*)d_in[2];
    const float* b1 = (const float*)d_in[3];
    const float* W2 = (const float*)d_in[4];
    const float* b2 = (const float*)d_in[5];
    const float* W3 = (const float*)d_in[6];
    const float* b3 = (const float*)d_in[7];
    const float* W4 = (const float*)d_in[8];
    const float* b4 = (const float*)d_in[9];
    const float* tx_eq    = (const float*)d_in[10];
    const float* tx_init  = (const float*)d_in[11];
    const float* tx_bound = (const float*)d_in[12];
    float* out = (float*)d_out;
    char* wpre = (char*)d_ws;     // needs 384KB

    hipFuncSetAttribute((const void*)pinn_mfma<4,32>,  hipFuncAttributeMaxDynamicSharedMemorySize, LDS_SZ);
    hipFuncSetAttribute((const void*)pinn_mfma<2,64>,  hipFuncAttributeMaxDynamicSharedMemorySize, LDS_SZ);
    hipFuncSetAttribute((const void*)pinn_mfma<1,128>, hipFuncAttributeMaxDynamicSharedMemorySize, LDS_SZ);

    prep_w<<<768, 256, 0, stream>>>(W1, W2, W3, wpre);
    pinn_mfma<4,32> <<<N_PTS/32,  512, LDS_SZ, stream>>>(W0,b0,b1,b2,b3,W4,b4,wpre,tx_eq,   out);
    pinn_mfma<2,64> <<<N_PTS/64,  512, LDS_SZ, stream>>>(W0,b0,b1,b2,b3,W4,b4,wpre,tx_init, out);
    pinn_mfma<1,128><<<N_PTS/128, 512, LDS_SZ, stream>>>(W0,b0,b1,b2,b3,W4,b4,wpre,tx_bound,out);
}

// Round 7
// 645.998 us; speedup vs baseline: 3.5950x; 1.0423x over previous
//
#include <hip/hip_runtime.h>
#include <math.h>

#define N_PTS 131072
#define HID   256

typedef __attribute__((ext_vector_type(8)))  _Float16 f16x8;
typedef __attribute__((ext_vector_type(4)))  float    f32x4;
typedef __attribute__((ext_vector_type(16))) float    f32x16;
typedef unsigned int u32;
typedef __attribute__((address_space(1))) const u32 gu32;
typedef __attribute__((address_space(3))) u32       lu32;

// LDS map (dynamic, 128 KiB): act[128][256] f16 (64KB) | W double-buffer (2 x 32KB)
#define LDS_HI  0
#define LDS_W   65536
#define LDS_SZ  131072

// act plane: [row][k] f16, 16B-slot XOR on (row&7) -> A-frag b128 reads uniform/bank
__device__ __forceinline__ int act_off(int row, int kbyte) {
    return row * 512 + (kbyte ^ ((row & 7) << 4));
}
// W period in LDS: [n][64k] f16 (transposed), 16B-slot XOR on (n&7)
__device__ __forceinline__ int w_off64(int n, int kg) {
    return n * 128 + ((kg ^ (n & 7)) << 4);
}
// h = tanh(z), f1 = 1 - h^2, via s = e^{2z}: h = 1 - 2/(s+1), f1 = 4s/(s+1)^2
__device__ __forceinline__ void tanh_f1(float z, float& h, float& f1) {
    float zc = fminf(fmaxf(z, -15.0f), 15.0f);
    float s  = __expf(2.0f * zc);
    float r  = __builtin_amdgcn_rcpf(s + 1.0f);
    h  = fmaf(-2.0f, r, 1.0f);
    f1 = 4.0f * s * r * r;
}

// Pre-cast W1..W3 to f16 (RN), transposed to [n][k], LDS swizzle pre-applied.
// d_ws: [layer 0..2][period 0..3] x 32KB. 384KB total.
__global__ void prep_w(const float* __restrict__ W1, const float* __restrict__ W2,
                       const float* __restrict__ W3, char* __restrict__ ws)
{
    int idx = blockIdx.x * 256 + threadIdx.x;     // 3*65536 elements
    int l = idx >> 16;
    int e = idx & 65535;
    int k = e >> 8, n = e & 255;
    const float* W = (l == 0) ? W1 : (l == 1) ? W2 : W3;
    float w = W[e];
    int period = k >> 6;
    int kk = k & 63;
    int byte_in = w_off64(n, kk >> 3) + (kk & 7) * 2;
    char* base = ws + (size_t)(l * 4 + period) * 32768;
    *(_Float16*)(base + byte_in) = (_Float16)w;
}

// Fused PINN forward + Taylor streams; 32x32x16 f16 MFMA, fp32 accum.
// Rows interleaved: GEMM row = S*p + s2 -> all S streams of a point land in
// consecutive C/D regs of one lane (32x32 layout: row=(reg&3)+8(reg>>2)+4(lane>>5)).
// 8 waves as 2 row-groups x 4 col-groups, each wave 2x2 tiles of 32x32.
template<int S, int PTS>
__global__ void __launch_bounds__(512, 1)
pinn_mfma(const float* __restrict__ W0, const float* __restrict__ b0,
          const float* __restrict__ b1, const float* __restrict__ b2,
          const float* __restrict__ b3,
          const float* __restrict__ W4, const float* __restrict__ b4,
          const char* __restrict__ wpre,
          const float* __restrict__ tx, float* __restrict__ out)
{
    extern __shared__ char lds[];
    const int tid  = threadIdx.x;
    const int lane = tid & 63;
    const int wid  = tid >> 6;
    const int wr   = wid & 1;          // row-group: row-tiles {2wr, 2wr+1}
    const int wc   = wid >> 1;         // col-group: col-tiles {2wc, 2wc+1}
    const int pbase = blockIdx.x * PTS;
    constexpr int CG = 512 / PTS;      // threads per point (layer 0)
    constexpr int NC = 256 / CG;       // cols per thread (layer 0)
    const int ep  = tid / CG;
    const int ec0 = (tid % CG) * NC;

    // issue stage of W period 0 first: HBM latency hides under layer 0
    {
        const char* src = wpre;
        char* dst = lds + LDS_W;
        #pragma unroll
        for (int q = 0; q < 4; ++q) {
            int o = (wid * 4 + q) * 1024;
            __builtin_amdgcn_global_load_lds((gu32*)(src + o + lane * 16),
                                             (lu32*)(dst + o), 16, 0, 0);
        }
    }

    // ---------------- layer 0: 2 -> 256 (elementwise into LDS act) ----------------
    {
        const float tt = tx[2 * (pbase + ep) + 0];
        const float xx = tx[2 * (pbase + ep) + 1];
        for (int cb = ec0; cb < ec0 + NC; cb += 8) {
            alignas(16) float w0r[8], w1r[8], bb[8];
            *(f32x4*)&w0r[0] = *(const f32x4*)(W0 + cb);
            *(f32x4*)&w0r[4] = *(const f32x4*)(W0 + cb + 4);
            *(f32x4*)&w1r[0] = *(const f32x4*)(W0 + HID + cb);
            *(f32x4*)&w1r[4] = *(const f32x4*)(W0 + HID + cb + 4);
            *(f32x4*)&bb[0]  = *(const f32x4*)(b0 + cb);
            *(f32x4*)&bb[4]  = *(const f32x4*)(b0 + cb + 4);
            f16x8 vhi[S];
            #pragma unroll
            for (int j = 0; j < 8; ++j) {
                float z = fmaf(tt, w0r[j], fmaf(xx, w1r[j], bb[j]));
                float h, f1;
                tanh_f1(z, h, f1);
                vhi[0][j] = (_Float16)h;
                if (S == 2) {
                    vhi[1][j] = (_Float16)(f1 * w0r[j]);
                } else if (S == 4) {
                    float d1 = w0r[j] + w1r[j];
                    float d2 = w0r[j] - w1r[j];
                    float f2 = -2.0f * h * f1;
                    vhi[1][j] = (_Float16)(f1 * d1);
                    vhi[2][j] = (_Float16)(f1 * d2);
                    vhi[3][j] = (_Float16)(f2 * d1 * d2);
                }
            }
            #pragma unroll
            for (int s2 = 0; s2 < S; ++s2) {
                int row = ep * S + s2;      // point-interleaved
                *(f16x8*)(lds + LDS_HI + act_off(row, cb * 2)) = vhi[s2];
            }
        }
    }

    // bias preload: one col per lane per col-tile
    const int c0 = (wc * 2) * 32 + (lane & 31);
    float bcv[3][2];
    bcv[0][0] = b1[c0]; bcv[0][1] = b1[c0 + 32];
    bcv[1][0] = b2[c0]; bcv[1][1] = b2[c0 + 32];
    bcv[2][0] = b3[c0]; bcv[2][1] = b3[c0 + 32];

    asm volatile("s_waitcnt lgkmcnt(0)" ::: "memory");   // act writes visible
    __builtin_amdgcn_sched_barrier(0);

    // ---------------- layers 1..3: 256 -> 256 ----------------
    #pragma unroll
    for (int l = 0; l < 3; ++l) {
        f32x16 acc[2][2];
        #pragma unroll
        for (int i = 0; i < 2; ++i)
            #pragma unroll
            for (int j = 0; j < 2; ++j)
                acc[i][j] = (f32x16){0.f,0.f,0.f,0.f,0.f,0.f,0.f,0.f,
                                     0.f,0.f,0.f,0.f,0.f,0.f,0.f,0.f};

        #pragma unroll
        for (int ph = 0; ph < 4; ++ph) {
            const int g = l * 4 + ph;
            __builtin_amdgcn_s_barrier();          // prev-phase readers done
            if (g < 11) {                          // prefetch next period
                const char* src = wpre + (size_t)(g + 1) * 32768;
                char* dst = lds + LDS_W + ((g + 1) & 1) * 32768;
                #pragma unroll
                for (int q = 0; q < 4; ++q) {
                    int o = (wid * 4 + q) * 1024;
                    __builtin_amdgcn_global_load_lds((gu32*)(src + o + lane * 16),
                                                     (lu32*)(dst + o), 16, 0, 0);
                }
                asm volatile("s_waitcnt vmcnt(4)" ::: "memory");   // own buf ready
            } else {
                asm volatile("s_waitcnt vmcnt(0)" ::: "memory");
            }
            __builtin_amdgcn_sched_barrier(0);

            const char* wb = lds + LDS_W + (g & 1) * 32768;
            #pragma unroll
            for (int ks = 0; ks < 4; ++ks) {
                const int kb = ph * 128 + ks * 32 + ((lane >> 5) << 4);
                const int kg = ks * 2 + (lane >> 5);
                f16x8 av[2], bv[2];
                #pragma unroll
                for (int i = 0; i < 2; ++i) {
                    const int row = (wr * 2 + i) * 32 + (lane & 31);
                    av[i] = *(const f16x8*)(lds + LDS_HI + act_off(row, kb));
                }
                #pragma unroll
                for (int j = 0; j < 2; ++j) {
                    const int n = (wc * 2 + j) * 32 + (lane & 31);
                    bv[j] = *(const f16x8*)(wb + w_off64(n, kg));
                }
                __builtin_amdgcn_s_setprio(1);
                acc[0][0] = __builtin_amdgcn_mfma_f32_32x32x16_f16(av[0], bv[0], acc[0][0], 0, 0, 0);
                acc[0][1] = __builtin_amdgcn_mfma_f32_32x32x16_f16(av[0], bv[1], acc[0][1], 0, 0, 0);
                acc[1][0] = __builtin_amdgcn_mfma_f32_32x32x16_f16(av[1], bv[0], acc[1][0], 0, 0, 0);
                acc[1][1] = __builtin_amdgcn_mfma_f32_32x32x16_f16(av[1], bv[1], acc[1][1], 0, 0, 0);
                __builtin_amdgcn_s_setprio(0);
            }
        }
        __builtin_amdgcn_s_barrier();   // all act/W reads of this layer done

        // ---- in-register epilogue ----
        // C/D: col = ctile*32 + (lane&31); row-in-tile = (reg&3)+8*(reg>>2)+4*(lane>>5)
        #pragma unroll
        for (int i = 0; i < 2; ++i) {
            #pragma unroll
            for (int j = 0; j < 2; ++j) {
                const int colj = (wc * 2 + j) * 32 + (lane & 31);
                const float bias = bcv[l][j];
                const int rtb = (wr * 2 + i) * 32 + 4 * (lane >> 5);
                #pragma unroll
                for (int q = 0; q < 4; ++q) {
                    const int rb = rtb + 8 * q;
                    if (S == 4) {
                        float z0 = acc[i][j][4*q+0] + bias;
                        float z1 = acc[i][j][4*q+1];
                        float z2 = acc[i][j][4*q+2];
                        float zm = acc[i][j][4*q+3];
                        float h, f1;
                        tanh_f1(z0, h, f1);
                        float f2 = -2.0f * h * f1;
                        *(_Float16*)(lds + LDS_HI + act_off(rb+0, colj*2)) = (_Float16)h;
                        *(_Float16*)(lds + LDS_HI + act_off(rb+1, colj*2)) = (_Float16)(f1 * z1);
                        *(_Float16*)(lds + LDS_HI + act_off(rb+2, colj*2)) = (_Float16)(f1 * z2);
                        *(_Float16*)(lds + LDS_HI + act_off(rb+3, colj*2)) =
                            (_Float16)(fmaf(f1, zm, f2 * z1 * z2));
                    } else if (S == 2) {
                        #pragma unroll
                        for (int pp = 0; pp < 2; ++pp) {
                            float z0 = acc[i][j][4*q+2*pp+0] + bias;
                            float zd = acc[i][j][4*q+2*pp+1];
                            float h, f1;
                            tanh_f1(z0, h, f1);
                            *(_Float16*)(lds + LDS_HI + act_off(rb+2*pp+0, colj*2)) = (_Float16)h;
                            *(_Float16*)(lds + LDS_HI + act_off(rb+2*pp+1, colj*2)) = (_Float16)(f1 * zd);
                        }
                    } else {
                        #pragma unroll
                        for (int m = 0; m < 4; ++m) {
                            float z0 = acc[i][j][4*q+m] + bias;
                            float h, f1;
                            tanh_f1(z0, h, f1);
                            *(_Float16*)(lds + LDS_HI + act_off(rb+m, colj*2)) = (_Float16)h;
                        }
                    }
                }
            }
        }
        asm volatile("s_waitcnt lgkmcnt(0)" ::: "memory");
        __builtin_amdgcn_sched_barrier(0);
    }
    __builtin_amdgcn_s_barrier();   // epilogue writes visible to all

    // ---------------- layer 4: 256 -> 1 ----------------
    if (S == 4) {
        // only the mixed stream (rows 4p+3) is needed
        const int p   = tid >> 4;     // 0..31
        const int seg = tid & 15;     // 16 lanes per point
        const int k0  = seg * 16;
        const int row = 4 * p + 3;
        float d = 0.0f;
        #pragma unroll
        for (int kb = 0; kb < 16; kb += 8) {
            f16x8 h8 = *(const f16x8*)(lds + LDS_HI + act_off(row, (k0 + kb) * 2));
            alignas(16) float wv[8];
            *(f32x4*)&wv[0] = *(const f32x4*)(W4 + k0 + kb);
            *(f32x4*)&wv[4] = *(const f32x4*)(W4 + k0 + kb + 4);
            #pragma unroll
            for (int j = 0; j < 8; ++j) d = fmaf((float)h8[j], wv[j], d);
        }
        #pragma unroll
        for (int off = 8; off > 0; off >>= 1) d += __shfl_down(d, off, 16);
        if (seg == 0) out[0 * N_PTS + pbase + p] = d;              // u_tt - u_xx
    } else {
        const int row = tid >> 2;     // 0..127
        const int seg = tid & 3;      // 4 lanes per row
        const int k0  = seg * 64;
        float d = 0.0f;
        #pragma unroll
        for (int kb = 0; kb < 64; kb += 8) {
            f16x8 h8 = *(const f16x8*)(lds + LDS_HI + act_off(row, (k0 + kb) * 2));
            alignas(16) float wv[8];
            *(f32x4*)&wv[0] = *(const f32x4*)(W4 + k0 + kb);
            *(f32x4*)&wv[4] = *(const f32x4*)(W4 + k0 + kb + 4);
            #pragma unroll
            for (int j = 0; j < 8; ++j) d = fmaf((float)h8[j], wv[j], d);
        }
        d += __shfl_down(d, 2, 4);
        d += __shfl_down(d, 1, 4);
        if (seg == 0) {
            if (S == 2) {
                const int p = row >> 1;
                if ((row & 1) == 0) out[1 * N_PTS + pbase + p] = d + b4[0];   // u_phi
                else                out[2 * N_PTS + pbase + p] = d;           // du/dt
            } else {
                out[3 * N_PTS + pbase + row] = d + b4[0];                     // u_bound
            }
        }
    }
}

extern "C" void kernel_launch(void* const* d_in, const int* in_sizes, int n_in,
                              void* d_out, int out_size, void* d_ws, size_t ws_size,
                              hipStream_t stream) {
    const float* W0 = (const float*)d_in[0];
    const float* b0 = (const float*)d_in[1];
    const float* W1 = (const float*)d_in[2];
    const float* b1 = (const float*)d_in[3];
    const float* W2 = (const float*)d_in[4];
    const float* b2 = (const float*)d_in[5];
    const float* W3 = (const float*)d_in[6];
    const float* b3 = (const float*)d_in[7];
    const float* W4 = (const float*)d_in[8];
    const float* b4 = (const float*)d_in[9];
    const float* tx_eq    = (const float*)d_in[10];
    const float* tx_init  = (const float*)d_in[11];
    const float* tx_bound = (const float*)d_in[12];
    float* out = (float*)d_out;
    char* wpre = (char*)d_ws;     // needs 384KB

    hipFuncSetAttribute((const void*)pinn_mfma<4,32>,  hipFuncAttributeMaxDynamicSharedMemorySize, LDS_SZ);
    hipFuncSetAttribute((const void*)pinn_mfma<2,64>,  hipFuncAttributeMaxDynamicSharedMemorySize, LDS_SZ);
    hipFuncSetAttribute((const void*)pinn_mfma<1,128>, hipFuncAttributeMaxDynamicSharedMemorySize, LDS_SZ);

    prep_w<<<768, 256, 0, stream>>>(W1, W2, W3, wpre);
    pinn_mfma<4,32> <<<N_PTS/32,  512, LDS_SZ, stream>>>(W0,b0,b1,b2,b3,W4,b4,wpre,tx_eq,   out);
    pinn_mfma<2,64> <<<N_PTS/64,  512, LDS_SZ, stream>>>(W0,b0,b1,b2,b3,W4,b4,wpre,tx_init, out);
    pinn_mfma<1,128><<<N_PTS/128, 512, LDS_SZ, stream>>>(W0,b0,b1,b2,b3,W4,b4,wpre,tx_bound,out);
}